// Round 3
// baseline (429.828 us; speedup 1.0000x reference)
//
#include <hip/hip_runtime.h>

#define G 8192
#define B 32
#define O 128
#define NROWS 4096             // stat partial rows: 2048 blocks * 2 pairs
#define NTOT 262144.0f         // B*G

typedef float f32x4 __attribute__((ext_vector_type(4)));
typedef _Float16 half8 __attribute__((ext_vector_type(8)));
typedef _Float16 half2v __attribute__((ext_vector_type(2)));

__device__ __forceinline__ float lrelu(float v) { return fmaxf(v, 0.1f * v); }

__device__ __forceinline__ unsigned pack2h(float lo, float hi) {
    half2v t; t.x = (_Float16)lo; t.y = (_Float16)hi;
    return __builtin_bit_cast(unsigned, t);
}

// ---- W fragment prep. Layout [m16][kk][lane][j]; o = m16*16+(lane&15),
//      k = kk*32 + (lane>>4)*8 + j   (contiguous sigma; x-side uses the same)
__device__ __forceinline__ void wfrag_one(const float* __restrict__ W, int ldw, int K, int KS,
                                          _Float16* __restrict__ out, int idx) {
    int j = idx & 7, lane = (idx >> 3) & 63, t = idx >> 9;
    int kk = t % KS, m16 = t / KS;
    int o = m16 * 16 + (lane & 15);
    int k = kk * 32 + ((lane >> 4) & 3) * 8 + j;
    float v;
    if (k < K)          v = W[o * ldw + k] + W[o * ldw + K + k];
    else if (k < K + 3) v = W[o * ldw + 2 * K + (k - K)];
    else                v = 0.f;
    out[idx] = (_Float16)v;
}

__global__ void prep_all(const float* __restrict__ W1, const float* __restrict__ W2,
                         const float* __restrict__ W3, const float* __restrict__ W4,
                         _Float16* __restrict__ wf1, _Float16* __restrict__ wf2,
                         _Float16* __restrict__ wf3, _Float16* __restrict__ wf4) {
    int idx = blockIdx.x * 256 + threadIdx.x;
    if (idx < 12288)                wfrag_one(W1, 131, 64, 3, wf1, idx);
    else if (idx < 12288 + 20480)   wfrag_one(W2, 259, 128, 5, wf2, idx - 12288);
    else if (idx < 12288 + 40960)   wfrag_one(W3, 259, 128, 5, wf3, idx - 12288 - 20480);
    else if (idx < 12288 + 61440)   wfrag_one(W4, 259, 128, 5, wf4, idx - 12288 - 40960);
}

// ---- transpose features -> xT[b][g][80] f16 (64 feat + 3 ev + pad0), and seed
//      y[b][g][128..135] with the same ev rows (written once, layers keep them).
__global__ __launch_bounds__(256) void transpose_in(
    const float* __restrict__ F, const float* __restrict__ EV,
    _Float16* __restrict__ xT, _Float16* __restrict__ Y) {
    __shared__ _Float16 tl[128 * 72];
    const int t = threadIdx.x, gblk = blockIdx.x, b = blockIdx.y;
    const int g0 = gblk * 128;
    for (int idx = t; idx < 8192; idx += 256) {
        int c = idx >> 7, gi = idx & 127;
        tl[gi * 72 + c] = (_Float16)F[((size_t)b * 64 + c) * G + g0 + gi];
    }
    __syncthreads();
    const int gi = t >> 1, h = t & 1;
    _Float16* dst = xT + ((size_t)b * G + g0 + gi) * 80;
#pragma unroll
    for (int j = 0; j < 4; ++j)
        *(half8*)(dst + h * 32 + j * 8) = *(const half8*)(tl + gi * 72 + h * 32 + j * 8);
    if (h == 0) {
        float e0 = EV[((size_t)b * 3 + 0) * G + g0 + gi];
        float e1 = EV[((size_t)b * 3 + 1) * G + g0 + gi];
        float e2 = EV[((size_t)b * 3 + 2) * G + g0 + gi];
        half8 ev8 = {};
        ev8[0] = (_Float16)e0; ev8[1] = (_Float16)e1; ev8[2] = (_Float16)e2;
        half8 z = {};
        *(half8*)(dst + 64) = ev8;
        *(half8*)(dst + 72) = z;
        *(half8*)(Y + ((size_t)b * G + g0 + gi) * 136 + 128) = ev8;
    }
}

// bias0[b][o] = -sum_c Wb1[o][c] * features[b][c][0]
__global__ void bias0_first(const float* __restrict__ X, const float* __restrict__ W,
                            float* __restrict__ bias) {
    __shared__ float x0[64];
    int b = blockIdx.x, o = threadIdx.x;
    if (o < 64) x0[o] = X[((size_t)b * 64 + o) * G];
    __syncthreads();
    float acc = 0.f;
    for (int c = 0; c < 64; ++c) acc += W[o * 131 + 64 + c] * x0[c];
    bias[b * O + o] = -acc;
}

__global__ void bias0_next(const _Float16* __restrict__ Y, const float* __restrict__ A,
                           const float* __restrict__ Cc, const float* __restrict__ W,
                           float* __restrict__ bias) {
    __shared__ float xn[128];
    int b = blockIdx.x, o = threadIdx.x;
    float v = (float)Y[((size_t)b * G) * 136 + o];   // column g=0, contiguous
    xn[o] = lrelu(A[o] * v + Cc[o]);
    __syncthreads();
    float acc = 0.f;
    for (int c = 0; c < 128; ++c) acc += W[o * 259 + 128 + c] * xn[c];
    bias[b * O + o] = -acc;
}

// ---- main layer: block = 128 g-rows x all 128 o. 4 waves: pair p=w&1 owns 4
//      16-g fragments, mhalf w>>1 owns o 0..63 / 64..127.
template<int KS, int SXI, int SXO, bool NORM>
__global__ __launch_bounds__(256) void edge_mfma(
    const _Float16* __restrict__ X,    // [B][G][SXI] (x rows + ev rows embedded)
    _Float16* __restrict__ Y,          // [B][G][SXO] raw pre-BN out (in-place ok)
    const _Float16* __restrict__ Wf,   // fragment-ordered effective weights
    const float* __restrict__ bias,    // [B][O]
    const _Float16* __restrict__ Ah, const _Float16* __restrict__ Ch, // f16 norm of input
    float* __restrict__ part)          // [NROWS][256]
{
    __shared__ _Float16 lds[128 * SXI + 32];
    const int tid  = threadIdx.x;
    const int lane = tid & 63;
    const int wave = tid >> 6;
    const int fr   = lane & 15;
    const int grp  = lane >> 4;
    const int p      = wave & 1;
    const int mhalf  = wave >> 1;
    const int gblk = blockIdx.x;      // 0..63
    const int b    = blockIdx.y;      // 0..31
    const int g0   = gblk * 128;

    // ---- stage: one contiguous chunk, fully coalesced uint4 copy
    constexpr int BYTES = 128 * SXI * 2;
    constexpr int NIT = (BYTES + 4095) / 4096;
    const char* src = (const char*)(X + ((size_t)b * G + g0) * SXI);
#pragma unroll
    for (int it = 0; it < NIT; ++it) {
        int off = it * 4096 + tid * 16;
        if (BYTES % 4096 == 0 || off < BYTES)
            *(uint4*)((char*)lds + off) = *(const uint4*)(src + off);
    }
    __syncthreads();

    // ---- preload A fragments + norm constants (registers, loop-invariant)
    half8 af[4][KS];
#pragma unroll
    for (int mf = 0; mf < 4; ++mf)
#pragma unroll
        for (int kk = 0; kk < KS; ++kk)
            af[mf][kk] = *(const half8*)(Wf + ((((mhalf * 4 + mf) * KS) + kk) * 64 + lane) * 8);

    half8 ah[KS > 1 ? KS - 1 : 1], ch[KS > 1 ? KS - 1 : 1];
    if (NORM) {
#pragma unroll
        for (int kk = 0; kk < KS - 1; ++kk) {
            ah[kk] = *(const half8*)(Ah + kk * 32 + grp * 8);
            ch[kk] = *(const half8*)(Ch + kk * 32 + grp * 8);
        }
    }

    f32x4 sacc[4], qacc[4];
#pragma unroll
    for (int mf = 0; mf < 4; ++mf) { sacc[mf] = (f32x4)0.f; qacc[mf] = (f32x4)0.f; }

#pragma unroll
    for (int nfl = 0; nfl < 4; ++nfl) {
        const int nf = p * 4 + nfl;
        const int grow = nf * 16 + fr;
        f32x4 acc[4];
#pragma unroll
        for (int mf = 0; mf < 4; ++mf) acc[mf] = (f32x4)0.f;

#pragma unroll
        for (int kk = 0; kk < KS; ++kk) {
            half8 bf = *(const half8*)(lds + grow * SXI + kk * 32 + grp * 8);
            if (NORM && kk < KS - 1) {
                half8 t = bf * ah[kk] + ch[kk];
                bf = __builtin_elementwise_max(t, t * (_Float16)0.1f);
            }
            if (kk == KS - 1) {
                if (grp != 0) bf = (half8)((_Float16)0);  // zero/ev-pad k-rows
            }
#pragma unroll
            for (int mf = 0; mf < 4; ++mf)
                acc[mf] = __builtin_amdgcn_mfma_f32_16x16x32_f16(af[mf][kk], bf, acc[mf], 0, 0, 0);
        }

        // epilogue: bias, stats accumulate, packed f16 store
#pragma unroll
        for (int mf = 0; mf < 4; ++mf) {
            float4 bv = *(const float4*)(bias + b * O + mhalf * 64 + mf * 16 + grp * 4);
            acc[mf][0] += bv.x; acc[mf][1] += bv.y; acc[mf][2] += bv.z; acc[mf][3] += bv.w;
            sacc[mf] += acc[mf];
            qacc[mf] += acc[mf] * acc[mf];
            uint2 w;
            w.x = pack2h(acc[mf][0], acc[mf][1]);
            w.y = pack2h(acc[mf][2], acc[mf][3]);
            *(uint2*)(Y + ((size_t)b * G + g0 + grow) * SXO + mhalf * 64 + mf * 16 + grp * 4) = w;
        }
    }

    // ---- one shuffle-reduce over the 16 g-columns (fr), then store partials
    const int row = ((b * 64 + gblk) * 2 + p) * 256;
#pragma unroll
    for (int mf = 0; mf < 4; ++mf) {
#pragma unroll
        for (int i = 0; i < 4; ++i) {
            float s = sacc[mf][i], q = qacc[mf][i];
            s += __shfl_xor(s, 1, 64); q += __shfl_xor(q, 1, 64);
            s += __shfl_xor(s, 2, 64); q += __shfl_xor(q, 2, 64);
            s += __shfl_xor(s, 4, 64); q += __shfl_xor(q, 4, 64);
            s += __shfl_xor(s, 8, 64); q += __shfl_xor(q, 8, 64);
            if (fr == 0) {
                int o = mhalf * 64 + mf * 16 + grp * 4 + i;
                part[row + o]       = s;
                part[row + 128 + o] = q;
            }
        }
    }
}

// per-channel: reduce partials -> a,c (f32 + f16 copies)
__global__ void finalize(const float* __restrict__ part, const float* __restrict__ gamma,
                         const float* __restrict__ beta, float* __restrict__ A,
                         float* __restrict__ Cc, _Float16* __restrict__ Ahh,
                         _Float16* __restrict__ Chh) {
    __shared__ float rs[256], rq[256];
    int o = blockIdx.x, t = threadIdx.x;
    float s = 0.f, q = 0.f;
    for (int r = t; r < NROWS; r += 256) {
        s += part[r * 256 + o];
        q += part[r * 256 + 128 + o];
    }
    rs[t] = s; rq[t] = q;
    __syncthreads();
    for (int w = 128; w > 0; w >>= 1) {
        if (t < w) { rs[t] += rs[t + w]; rq[t] += rq[t + w]; }
        __syncthreads();
    }
    if (t == 0) {
        float mean = rs[0] / NTOT;
        float var  = rq[0] / NTOT - mean * mean;
        float a = gamma[o] * rsqrtf(var + 1e-5f);
        float c = beta[o] - mean * a;
        A[o] = a; Cc[o] = c;
        Ahh[o] = (_Float16)a; Chh[o] = (_Float16)c;
    }
}

// out[b][o] = max_g lrelu(a*y+c); lrelu(affine) is monotone, so reduce raw
// max AND min of y, pick by sign of a, apply once.
__global__ __launch_bounds__(1024) void maxout(const _Float16* __restrict__ Y,
                                               const float* __restrict__ A,
                                               const float* __restrict__ Cc,
                                               float* __restrict__ out) {
    __shared__ _Float16 smx[64 * 136], smn[64 * 136];
    const int t = threadIdx.x, b = blockIdx.x;
    const int o8 = (t & 15) * 8, gs = t >> 4;           // gs: 0..63
    const _Float16* base = Y + ((size_t)b * G) * 136 + o8;
    half8 mx = *(const half8*)(base + (size_t)gs * 136);
    half8 mn = mx;
    for (int g = gs + 64; g < G; g += 64) {
        half8 v = *(const half8*)(base + (size_t)g * 136);
        mx = __builtin_elementwise_max(mx, v);
        mn = __builtin_elementwise_min(mn, v);
    }
    *(half8*)(smx + gs * 136 + o8) = mx;
    *(half8*)(smn + gs * 136 + o8) = mn;
    __syncthreads();
    if (t < 128) {
        float vmx = -3.4e38f, vmn = 3.4e38f;
        for (int i = 0; i < 64; ++i) {
            vmx = fmaxf(vmx, (float)smx[i * 136 + t]);
            vmn = fminf(vmn, (float)smn[i * 136 + t]);
        }
        float a = A[t], c = Cc[t];
        float v = (a >= 0.f ? vmx : vmn);
        out[b * O + t] = lrelu(a * v + c);
    }
}

extern "C" void kernel_launch(void* const* d_in, const int* in_sizes, int n_in,
                              void* d_out, int out_size, void* d_ws, size_t ws_size,
                              hipStream_t stream) {
    const float* feat = (const float*)d_in[0];
    const float* ev   = (const float*)d_in[1];
    const float* W1   = (const float*)d_in[2];
    const float* W2   = (const float*)d_in[3];
    const float* W3   = (const float*)d_in[4];
    const float* W4   = (const float*)d_in[5];
    const float* g1   = (const float*)d_in[6];
    const float* b1   = (const float*)d_in[7];
    const float* g2   = (const float*)d_in[8];
    const float* b2   = (const float*)d_in[9];
    const float* g3   = (const float*)d_in[10];
    const float* b3   = (const float*)d_in[11];
    const float* g4   = (const float*)d_in[12];
    const float* b4   = (const float*)d_in[13];

    _Float16* y  = (_Float16*)d_ws;            // 32*8192*136 = 35,651,584 (+64 pad)
    _Float16* xT = y + 35651648;               // 32*8192*80 = 20,971,520 (+64 pad)
    float* part  = (float*)(xT + 20971584);    // 4096*256 = 1,048,576 floats
    float* bias  = part + 1048576;             // 4096
    float* Aar   = bias + 4096;                // 128
    float* Car   = Aar + 128;                  // 128
    _Float16* wf1 = (_Float16*)(Car + 128);    // 12288
    _Float16* wf2 = wf1 + 12288;               // 20480
    _Float16* wf3 = wf2 + 20480;               // 20480
    _Float16* wf4 = wf3 + 20480;               // 20480
    _Float16* Ah  = wf4 + 20480;               // 192
    _Float16* Ch  = Ah + 192;                  // 192

    dim3 tg(64, 32);
    prep_all<<<288, 256, 0, stream>>>(W1, W2, W3, W4, wf1, wf2, wf3, wf4);
    transpose_in<<<tg, 256, 0, stream>>>(feat, ev, xT, y);
    bias0_first<<<32, 128, 0, stream>>>(feat, W1, bias);

    edge_mfma<3, 80, 136, false><<<tg, 256, 0, stream>>>(xT, y, wf1, bias, Ah, Ch, part);
    finalize<<<128, 256, 0, stream>>>(part, g1, b1, Aar, Car, Ah, Ch);

    bias0_next<<<32, 128, 0, stream>>>(y, Aar, Car, W2, bias);
    edge_mfma<5, 136, 136, true><<<tg, 256, 0, stream>>>(y, y, wf2, bias, Ah, Ch, part);
    finalize<<<128, 256, 0, stream>>>(part, g2, b2, Aar, Car, Ah, Ch);

    bias0_next<<<32, 128, 0, stream>>>(y, Aar, Car, W3, bias);
    edge_mfma<5, 136, 136, true><<<tg, 256, 0, stream>>>(y, y, wf3, bias, Ah, Ch, part);
    finalize<<<128, 256, 0, stream>>>(part, g3, b3, Aar, Car, Ah, Ch);

    bias0_next<<<32, 128, 0, stream>>>(y, Aar, Car, W4, bias);
    edge_mfma<5, 136, 136, true><<<tg, 256, 0, stream>>>(y, y, wf4, bias, Ah, Ch, part);
    finalize<<<128, 256, 0, stream>>>(part, g4, b4, Aar, Car, Ah, Ch);

    maxout<<<32, 1024, 0, stream>>>(y, Aar, Car, (float*)d_out);
}